// Round 6
// baseline (513.257 us; speedup 1.0000x reference)
//
#include <hip/hip_runtime.h>
#include <cstdint>
#include <cstddef>

typedef float v4f __attribute__((ext_vector_type(4)));
typedef int   v4i __attribute__((ext_vector_type(4)));

// Problem constants (from reference): B=4, N=65536, K=16, D=8, OUT=8
namespace {
constexpr int Bn = 4;
constexpr int Nn = 65536;
constexpr int Kn = 16;
constexpr int NK = Nn * Kn;          // 1<<20
constexpr int TOTAL = Bn * NK;       // 1<<22 = 4,194,304
constexpr float COUNT_F = 4194304.0f;
constexpr float EPS = 1e-6f;
constexpr float SLOPE = 0.2f;
// out0 = (B,16,N,K) then out1 = (B,8,N,K), concatenated flat
constexpr long long OUT0_TOTAL = (long long)Bn * 16 * NK;  // 67,108,864
}

// ws layout (bytes):
//   [0, 416)            : stats — [0..7]=sum, [8..15]=sumsq, [16..95]=fused W, [96..103]=fused b
//   [1024, 1024+4MB)    : cpad  — coords padded to float4, B*N (1 MB/batch)
//   [1024+4MB, +8MB)    : tf    — features transposed to (B,N,8), 2x float4 (2 MB/batch)

// ---------------- fused prep || reduce ----------------
// Even blocks: reduce role (one thread per (b,n); reads RAW coords -> no cpad dep;
//              16 neighbor gathers in 2 half-batches of 8 -> MLP=8).
// Odd blocks:  prep role (build cpad + tf for the output pass).
// Roles interleave by parity so both are co-resident: prep's streaming waves fill
// reduce's gather-latency stalls. Physical XCD = blockIdx%8 (round-robin dispatch):
// even blocks sit on XCDs {0,2,4,6}; batch b = (blockIdx%8)>>1 -> one batch per
// reduce-XCD, coords (768 KB/batch) L2-resident.
template <bool PREP>
__global__ __launch_bounds__(256, 4) void prep_reduce_kernel(
    const float* __restrict__ coords,     // (B,N,3)
    const float* __restrict__ features,   // (B,8,N)
    const v4i*   __restrict__ nbr4,       // (B,N,K/4) int4
    const float* __restrict__ conv_w,     // (8,10)
    const float* __restrict__ conv_b,     // (8,)
    float* __restrict__ stats,
    v4f* __restrict__ cpad,               // B*N
    v4f* __restrict__ tf)                 // B*N*2
{
    if (blockIdx.x & 1) {
        // ---------------- prep role ----------------
        if (!PREP) return;
        int t = (int)(blockIdx.x >> 1) * 256 + threadIdx.x;   // 0 .. B*N-1
        int b = t >> 16;
        int n = t & (Nn - 1);
        const float* c = coords + (size_t)t * 3;
        v4f cv = {c[0], c[1], c[2], 0.0f};
        __builtin_nontemporal_store(cv, &cpad[t]);
        const float* fb = features + (size_t)b * 8 * Nn + n;
        v4f lo = {fb[0 * Nn], fb[1 * Nn], fb[2 * Nn], fb[3 * Nn]};
        v4f hi = {fb[4 * Nn], fb[5 * Nn], fb[6 * Nn], fb[7 * Nn]};
        __builtin_nontemporal_store(lo, &tf[2 * t]);
        __builtin_nontemporal_store(hi, &tf[2 * t + 1]);
        return;
    }

    // ---------------- reduce role ----------------
    float w[80];
    #pragma unroll
    for (int i = 0; i < 80; i++) w[i] = conv_w[i];   // uniform addr -> s_load
    float bb8[8];
    #pragma unroll
    for (int i = 0; i < 8; i++) bb8[i] = conv_b[i];

    int b = ((int)blockIdx.x & 7) >> 1;              // one batch per even XCD
    int m = (int)blockIdx.x >> 3;                    // 0..255 within batch
    int n = m * 256 + (int)threadIdx.x;              // 0..65535: this thread's point

    const float* cb = coords + (size_t)b * Nn * 3;
    float ex = cb[n * 3], ey = cb[n * 3 + 1], ez = cb[n * 3 + 2];

    // all 16 neighbor indices up front (4 x int4, 64B contiguous per thread)
    int id[16];
    #pragma unroll
    for (int j = 0; j < 4; j++) {
        v4i q = __builtin_nontemporal_load(&nbr4[((size_t)b << 18) + (size_t)(n << 2) + j]);
        id[4 * j]     = q.x;
        id[4 * j + 1] = q.y;
        id[4 * j + 2] = q.z;
        id[4 * j + 3] = q.w;
    }

    float s[8], sq[8];
    #pragma unroll
    for (int i = 0; i < 8; i++) { s[i] = 0.0f; sq[i] = 0.0f; }

    // two half-batches of 8: gathers issued together (MLP=8), then compute
    #pragma unroll
    for (int h = 0; h < 2; h++) {
        float px[8], py[8], pz[8];
        #pragma unroll
        for (int k = 0; k < 8; k++) {
            int idx = id[h * 8 + k];
            px[k] = cb[idx * 3];
            py[k] = cb[idx * 3 + 1];
            pz[k] = cb[idx * 3 + 2];
        }
        #pragma unroll
        for (int k = 0; k < 8; k++) {
            float rx = ex - px[k], ry = ey - py[k], rz = ez - pz[k];
            float dist = sqrtf(rx * rx + ry * ry + rz * rz);
            float rf[10] = {dist, rx, ry, rz, ex, ey, ez, px[k], py[k], pz[k]};
            #pragma unroll
            for (int o = 0; o < 8; o++) {
                float y = bb8[o];
                #pragma unroll
                for (int c = 0; c < 10; c++) y = fmaf(w[o * 10 + c], rf[c], y);
                s[o] += y;
                sq[o] = fmaf(y, y, sq[o]);
            }
        }
    }

    // wave-64 butterfly reduction of 16 values
    #pragma unroll
    for (int i = 0; i < 8; i++) {
        #pragma unroll
        for (int off = 32; off > 0; off >>= 1) {
            s[i]  += __shfl_xor(s[i], off, 64);
            sq[i] += __shfl_xor(sq[i], off, 64);
        }
    }
    __shared__ float ls[4][16];
    int lane = threadIdx.x & 63;
    int wv = threadIdx.x >> 6;
    if (lane == 0) {
        #pragma unroll
        for (int i = 0; i < 8; i++) { ls[wv][i] = s[i]; ls[wv][8 + i] = sq[i]; }
    }
    __syncthreads();
    if (threadIdx.x < 16) {
        float a = ls[0][threadIdx.x] + ls[1][threadIdx.x]
                + ls[2][threadIdx.x] + ls[3][threadIdx.x];
        atomicAdd(&stats[threadIdx.x], a);
    }
}

// ---------------- finalize: fold BN into conv weights (kept separate ON PURPOSE:
// output_kernel s_loads the fused coeffs -> SGPR file, zero VGPR pressure) ----------------
__global__ void finalize_kernel(
    const float* __restrict__ conv_w,
    const float* __restrict__ conv_b,
    const float* __restrict__ gamma,
    const float* __restrict__ beta,
    float* __restrict__ stats)
{
    int j = threadIdx.x;
    if (j >= 88) return;
    int o = (j < 80) ? (j / 10) : (j - 80);
    float mean = stats[o] * (1.0f / COUNT_F);
    float var = stats[8 + o] * (1.0f / COUNT_F) - mean * mean;
    var = fmaxf(var, 0.0f);
    float scale = gamma[o] * rsqrtf(var + EPS);
    if (j < 80) stats[16 + j] = conv_w[j] * scale;                    // fused W
    else        stats[96 + o] = (conv_b[o] - mean) * scale + beta[o]; // fused b
}

// ---------------- pass 2: recompute y (fused BN), gather nf, write outputs ----------------
// R1-exact structure (measured best): one k-quad per thread, 12 gathers batched,
// all 24 output channels as float4 nontemporal stores, XCD-pinned batch mapping.
template <bool PREP>
__global__ __launch_bounds__(256) void output_kernel(
    const v4i* __restrict__ nbr4,
    const v4f* __restrict__ cpad,
    const float* __restrict__ coords,
    const v4f* __restrict__ tf,           // (B,N,8) as 2x float4
    const float* __restrict__ features,   // raw (B,8,N) for fallback
    const float* __restrict__ stats,
    float* __restrict__ out)
{
    float w[80];
    #pragma unroll
    for (int i = 0; i < 80; i++) w[i] = stats[16 + i];  // uniform addr -> s_load (SGPR)
    float bb[8];
    #pragma unroll
    for (int i = 0; i < 8; i++) bb[i] = stats[96 + i];

    int xcd = blockIdx.x & 7;
    int b   = xcd >> 1;                                  // 2 XCDs per batch
    int wb  = ((blockIdx.x >> 3) << 1) | (xcd & 1);      // 0..1023
    int ql  = wb * blockDim.x + threadIdx.x;             // 0..262143 (quad id in batch)
    int n   = ql >> 2;

    v4i idx = __builtin_nontemporal_load(&nbr4[((size_t)b << 18) + ql]);
    int id[4] = {idx.x, idx.y, idx.z, idx.w};

    const float* cb = coords + (size_t)b * Nn * 3;
    float ex, ey, ez;
    if (PREP) {
        v4f e = cpad[(b << 16) + n];
        ex = e.x; ey = e.y; ez = e.z;
    } else {
        ex = cb[n * 3]; ey = cb[n * 3 + 1]; ez = cb[n * 3 + 2];
    }

    float* o0 = out + ((size_t)b << 24) + (size_t)ql * 4;           // b*16*NK + r
    float* o1 = out + OUT0_TOTAL + ((size_t)(b * 8) << 20) + (size_t)ql * 4;

    if (PREP) {
        // ---- gathers: issue all loads up front (cpad + tf) ----
        v4f qc[4], lo[4], hi[4];
        #pragma unroll
        for (int k = 0; k < 4; k++) {
            qc[k] = cpad[(b << 16) + id[k]];
            lo[k] = tf[2 * ((b << 16) + id[k])];
            hi[k] = tf[2 * ((b << 16) + id[k]) + 1];
        }
        // nf -> out0 channels 0..7 (transpose k-major -> channel-major)
        #pragma unroll
        for (int c = 0; c < 4; c++) {
            v4f vlo = {lo[0][c], lo[1][c], lo[2][c], lo[3][c]};
            v4f vhi = {hi[0][c], hi[1][c], hi[2][c], hi[3][c]};
            __builtin_nontemporal_store(vlo, (v4f*)(o0 + (size_t)c * NK));
            __builtin_nontemporal_store(vhi, (v4f*)(o0 + (size_t)(4 + c) * NK));
        }
        // y channels -> out0 channels 8..15 and out1
        float acc[8][4];
        #pragma unroll
        for (int k = 0; k < 4; k++) {
            float rx = ex - qc[k].x, ry = ey - qc[k].y, rz = ez - qc[k].z;
            float dist = sqrtf(rx * rx + ry * ry + rz * rz);
            float rf[10] = {dist, rx, ry, rz, ex, ey, ez, qc[k].x, qc[k].y, qc[k].z};
            #pragma unroll
            for (int o = 0; o < 8; o++) {
                float y = bb[o];
                #pragma unroll
                for (int c = 0; c < 10; c++) y = fmaf(w[o * 10 + c], rf[c], y);
                acc[o][k] = fmaxf(y, SLOPE * y);   // LeakyReLU(0.2)
            }
        }
        #pragma unroll
        for (int o = 0; o < 8; o++) {
            v4f v = {acc[o][0], acc[o][1], acc[o][2], acc[o][3]};
            __builtin_nontemporal_store(v, (v4f*)(o0 + (size_t)(8 + o) * NK));
            __builtin_nontemporal_store(v, (v4f*)(o1 + (size_t)o * NK));
        }
    } else {
        // ---- fallback: raw gathers ----
        const float* fb = features + (size_t)b * 8 * Nn;
        #pragma unroll
        for (int d = 0; d < 8; d++) {
            v4f v = {fb[(size_t)d * Nn + id[0]], fb[(size_t)d * Nn + id[1]],
                     fb[(size_t)d * Nn + id[2]], fb[(size_t)d * Nn + id[3]]};
            __builtin_nontemporal_store(v, (v4f*)(o0 + (size_t)d * NK));
        }
        float acc[8][4];
        #pragma unroll
        for (int k = 0; k < 4; k++) {
            float nx = cb[id[k] * 3], ny = cb[id[k] * 3 + 1], nz = cb[id[k] * 3 + 2];
            float rx = ex - nx, ry = ey - ny, rz = ez - nz;
            float dist = sqrtf(rx * rx + ry * ry + rz * rz);
            float rf[10] = {dist, rx, ry, rz, ex, ey, ez, nx, ny, nz};
            #pragma unroll
            for (int o = 0; o < 8; o++) {
                float y = bb[o];
                #pragma unroll
                for (int c = 0; c < 10; c++) y = fmaf(w[o * 10 + c], rf[c], y);
                acc[o][k] = fmaxf(y, SLOPE * y);
            }
        }
        #pragma unroll
        for (int o = 0; o < 8; o++) {
            v4f v = {acc[o][0], acc[o][1], acc[o][2], acc[o][3]};
            __builtin_nontemporal_store(v, (v4f*)(o0 + (size_t)(8 + o) * NK));
            __builtin_nontemporal_store(v, (v4f*)(o1 + (size_t)o * NK));
        }
    }
}

extern "C" void kernel_launch(void* const* d_in, const int* in_sizes, int n_in,
                              void* d_out, int out_size, void* d_ws, size_t ws_size,
                              hipStream_t stream) {
    const float* coords   = (const float*)d_in[0];   // (4,65536,3)
    const float* features = (const float*)d_in[1];   // (4,8,65536,1)
    const int*   nbr      = (const int*)d_in[2];     // (4,65536,16)
    const float* conv_w   = (const float*)d_in[3];   // (8,10)
    const float* conv_b   = (const float*)d_in[4];   // (8,)
    const float* gamma    = (const float*)d_in[5];   // (8,)
    const float* beta     = (const float*)d_in[6];   // (8,)
    float* out = (float*)d_out;
    const v4i* nbr4 = (const v4i*)nbr;

    float* stats = (float*)d_ws;
    const size_t CPAD_OFF = 1024;
    const size_t CPAD_BYTES = (size_t)Bn * Nn * 4 * sizeof(float);   // 4 MB
    const size_t TF_OFF = CPAD_OFF + CPAD_BYTES;
    const size_t TF_BYTES = (size_t)Bn * Nn * 8 * sizeof(float);     // 8 MB
    const size_t NEED = TF_OFF + TF_BYTES;
    v4f* cpad = (v4f*)((char*)d_ws + CPAD_OFF);
    v4f* tf   = (v4f*)((char*)d_ws + TF_OFF);

    // zero the 16 stat accumulators (capture-safe async memset; avoids an init
    // race now that prep runs concurrently with reduce in the fused kernel)
    hipMemsetAsync(stats, 0, 16 * sizeof(float), stream);

    const bool prep = (ws_size >= NEED);
    if (prep) {
        prep_reduce_kernel<true><<<2048, 256, 0, stream>>>(
            coords, features, nbr4, conv_w, conv_b, stats, cpad, tf);
    } else {
        prep_reduce_kernel<false><<<2048, 256, 0, stream>>>(
            coords, features, nbr4, conv_w, conv_b, stats, cpad, tf);
    }
    finalize_kernel<<<1, 128, 0, stream>>>(conv_w, conv_b, gamma, beta, stats);
    if (prep)
        output_kernel<true><<<4096, 256, 0, stream>>>(nbr4, cpad, coords, tf, features, stats, out);
    else
        output_kernel<false><<<4096, 256, 0, stream>>>(nbr4, cpad, coords, tf, features, stats, out);
}

// Round 7
// 472.977 us; speedup vs baseline: 1.0852x; 1.0852x over previous
//
#include <hip/hip_runtime.h>
#include <cstdint>
#include <cstddef>

typedef float v4f __attribute__((ext_vector_type(4)));
typedef int   v4i __attribute__((ext_vector_type(4)));

// Problem constants (from reference): B=4, N=65536, K=16, D=8, OUT=8
namespace {
constexpr int Bn = 4;
constexpr int Nn = 65536;
constexpr int Kn = 16;
constexpr int NK = Nn * Kn;          // 1<<20
constexpr int TOTAL = Bn * NK;       // 1<<22 = 4,194,304
constexpr float COUNT_F = 4194304.0f;
constexpr float EPS = 1e-6f;
constexpr float SLOPE = 0.2f;
// out0 = (B,16,N,K) then out1 = (B,8,N,K), concatenated flat
constexpr long long OUT0_TOTAL = (long long)Bn * 16 * NK;  // 67,108,864
}

// ws layout (bytes):
//   [0, 416)            : stats — [0..7]=sum, [8..15]=sumsq, [16..95]=fused W, [96..103]=fused b
//   [1024, 1024+4MB)    : cpad  — coords padded to float4, B*N (1 MB/batch)
//   [1024+4MB, +8MB)    : tf    — features transposed to (B,N,8), 2x float4 (2 MB/batch)

// ---------------- prep: zero stats, pad coords, transpose features (R1-exact) ----------------
__global__ __launch_bounds__(256) void prep_kernel(
    const float* __restrict__ coords,     // (B,N,3)
    const float* __restrict__ features,   // (B,8,N)
    float* __restrict__ stats,
    v4f* __restrict__ cpad,               // B*N
    v4f* __restrict__ tf)                 // B*N*2
{
    if (blockIdx.x == 0 && threadIdx.x < 16) stats[threadIdx.x] = 0.0f;
    int t = blockIdx.x * blockDim.x + threadIdx.x;   // 0 .. B*N-1
    if (t >= Bn * Nn) return;
    int b = t >> 16;             // N = 65536
    int n = t & (Nn - 1);
    const float* c = coords + (size_t)t * 3;
    v4f cv = {c[0], c[1], c[2], 0.0f};
    cpad[t] = cv;
    const float* fb = features + (size_t)b * 8 * Nn + n;
    v4f lo = {fb[0 * Nn], fb[1 * Nn], fb[2 * Nn], fb[3 * Nn]};
    v4f hi = {fb[4 * Nn], fb[5 * Nn], fb[6 * Nn], fb[7 * Nn]};
    tf[2 * t]     = lo;
    tf[2 * t + 1] = hi;
}

// ---------------- fallback stats init (no-prep path) ----------------
__global__ void init_kernel(float* __restrict__ stats) {
    if (threadIdx.x < 16) stats[threadIdx.x] = 0.0f;
}

// ---------------- pass 1: per-channel sum & sumsq of pre-BN y ----------------
// RESTRUCTURED (single-variable change this round): one thread per (b,n).
// All 4 nbr int4 loads + center issued up front; 16 cpad gathers in two static
// half-batches of 8 -> MLP=8, no serialized grid-stride iterations (R1 had 4
// dependent iterations with runtime stride, MLP~4). Gathers stay on cpad
// (one aligned 16B line per neighbor). XCD-pinned: batch = (blockIdx%8)>>1,
// 1 MB cpad/batch resident in its XCD-pair L2.
template <bool PREP>
__global__ __launch_bounds__(256) void reduce_kernel(
    const v4i* __restrict__ nbr4,         // (B,N,K/4) int4
    const v4f* __restrict__ cpad,
    const float* __restrict__ coords,
    const float* __restrict__ conv_w,     // (8,10)
    const float* __restrict__ conv_b,     // (8,)
    float* __restrict__ stats)
{
    float w[80];
    #pragma unroll
    for (int i = 0; i < 80; i++) w[i] = conv_w[i];   // uniform addr -> s_load (SGPR)
    float bb8[8];
    #pragma unroll
    for (int i = 0; i < 8; i++) bb8[i] = conv_b[i];

    int xcd = (int)blockIdx.x & 7;
    int b   = xcd >> 1;                                  // one batch per XCD pair
    int wb  = (((int)blockIdx.x >> 3) << 1) | (xcd & 1); // 0..255 within batch
    int n   = wb * 256 + (int)threadIdx.x;               // 0..65535

    // all 16 neighbor indices up front (4 x int4 = 64B contiguous)
    int id[16];
    #pragma unroll
    for (int j = 0; j < 4; j++) {
        v4i q = __builtin_nontemporal_load(&nbr4[((size_t)b << 18) + (size_t)(n << 2) + j]);
        id[4 * j]     = q.x;
        id[4 * j + 1] = q.y;
        id[4 * j + 2] = q.z;
        id[4 * j + 3] = q.w;
    }

    float ex, ey, ez;
    const float* cb = coords + (size_t)b * Nn * 3;
    if (PREP) {
        v4f e = cpad[(b << 16) + n];
        ex = e.x; ey = e.y; ez = e.z;
    } else {
        ex = cb[n * 3]; ey = cb[n * 3 + 1]; ez = cb[n * 3 + 2];
    }

    float s[8], sq[8];
    #pragma unroll
    for (int i = 0; i < 8; i++) { s[i] = 0.0f; sq[i] = 0.0f; }

    // two static half-batches of 8: gathers issued together (MLP=8), then compute
    #pragma unroll
    for (int h = 0; h < 2; h++) {
        v4f p[8];
        if (PREP) {
            #pragma unroll
            for (int k = 0; k < 8; k++) p[k] = cpad[(b << 16) + id[h * 8 + k]];
        } else {
            #pragma unroll
            for (int k = 0; k < 8; k++) {
                int idx = id[h * 8 + k];
                p[k] = (v4f){cb[idx * 3], cb[idx * 3 + 1], cb[idx * 3 + 2], 0.0f};
            }
        }
        #pragma unroll
        for (int k = 0; k < 8; k++) {
            float rx = ex - p[k].x, ry = ey - p[k].y, rz = ez - p[k].z;
            float dist = sqrtf(rx * rx + ry * ry + rz * rz);
            float rf[10] = {dist, rx, ry, rz, ex, ey, ez, p[k].x, p[k].y, p[k].z};
            #pragma unroll
            for (int o = 0; o < 8; o++) {
                float y = bb8[o];
                #pragma unroll
                for (int c = 0; c < 10; c++) y = fmaf(w[o * 10 + c], rf[c], y);
                s[o] += y;
                sq[o] = fmaf(y, y, sq[o]);
            }
        }
    }

    // wave-64 butterfly reduction of 16 values
    #pragma unroll
    for (int i = 0; i < 8; i++) {
        #pragma unroll
        for (int off = 32; off > 0; off >>= 1) {
            s[i]  += __shfl_xor(s[i], off, 64);
            sq[i] += __shfl_xor(sq[i], off, 64);
        }
    }
    __shared__ float ls[4][16];
    int lane = threadIdx.x & 63;
    int wv = threadIdx.x >> 6;
    if (lane == 0) {
        #pragma unroll
        for (int i = 0; i < 8; i++) { ls[wv][i] = s[i]; ls[wv][8 + i] = sq[i]; }
    }
    __syncthreads();
    if (threadIdx.x < 16) {
        float a = ls[0][threadIdx.x] + ls[1][threadIdx.x]
                + ls[2][threadIdx.x] + ls[3][threadIdx.x];
        atomicAdd(&stats[threadIdx.x], a);
    }
}

// ---------------- finalize: fold BN into conv weights (kept separate ON PURPOSE:
// output_kernel s_loads the fused coeffs -> SGPR file, zero VGPR pressure) ----------------
__global__ void finalize_kernel(
    const float* __restrict__ conv_w,
    const float* __restrict__ conv_b,
    const float* __restrict__ gamma,
    const float* __restrict__ beta,
    float* __restrict__ stats)
{
    int j = threadIdx.x;
    if (j >= 88) return;
    int o = (j < 80) ? (j / 10) : (j - 80);
    float mean = stats[o] * (1.0f / COUNT_F);
    float var = stats[8 + o] * (1.0f / COUNT_F) - mean * mean;
    var = fmaxf(var, 0.0f);
    float scale = gamma[o] * rsqrtf(var + EPS);
    if (j < 80) stats[16 + j] = conv_w[j] * scale;                    // fused W
    else        stats[96 + o] = (conv_b[o] - mean) * scale + beta[o]; // fused b
}

// ---------------- pass 2 (R1-exact, measured best): recompute y, gather nf, write ----------------
template <bool PREP>
__global__ __launch_bounds__(256) void output_kernel(
    const v4i* __restrict__ nbr4,
    const v4f* __restrict__ cpad,
    const float* __restrict__ coords,
    const v4f* __restrict__ tf,           // (B,N,8) as 2x float4
    const float* __restrict__ features,   // raw (B,8,N) for fallback
    const float* __restrict__ stats,
    float* __restrict__ out)
{
    float w[80];
    #pragma unroll
    for (int i = 0; i < 80; i++) w[i] = stats[16 + i];  // uniform addr -> s_load (SGPR)
    float bb[8];
    #pragma unroll
    for (int i = 0; i < 8; i++) bb[i] = stats[96 + i];

    int xcd = blockIdx.x & 7;
    int b   = xcd >> 1;                                  // 2 XCDs per batch
    int wb  = ((blockIdx.x >> 3) << 1) | (xcd & 1);      // 0..1023
    int ql  = wb * blockDim.x + threadIdx.x;             // 0..262143 (quad id in batch)
    int n   = ql >> 2;

    v4i idx = __builtin_nontemporal_load(&nbr4[((size_t)b << 18) + ql]);
    int id[4] = {idx.x, idx.y, idx.z, idx.w};

    const float* cb = coords + (size_t)b * Nn * 3;
    float ex, ey, ez;
    if (PREP) {
        v4f e = cpad[(b << 16) + n];
        ex = e.x; ey = e.y; ez = e.z;
    } else {
        ex = cb[n * 3]; ey = cb[n * 3 + 1]; ez = cb[n * 3 + 2];
    }

    float* o0 = out + ((size_t)b << 24) + (size_t)ql * 4;           // b*16*NK + r
    float* o1 = out + OUT0_TOTAL + ((size_t)(b * 8) << 20) + (size_t)ql * 4;

    if (PREP) {
        // ---- gathers: issue all loads up front (cpad + tf) ----
        v4f qc[4], lo[4], hi[4];
        #pragma unroll
        for (int k = 0; k < 4; k++) {
            qc[k] = cpad[(b << 16) + id[k]];
            lo[k] = tf[2 * ((b << 16) + id[k])];
            hi[k] = tf[2 * ((b << 16) + id[k]) + 1];
        }
        // nf -> out0 channels 0..7 (transpose k-major -> channel-major)
        #pragma unroll
        for (int c = 0; c < 4; c++) {
            v4f vlo = {lo[0][c], lo[1][c], lo[2][c], lo[3][c]};
            v4f vhi = {hi[0][c], hi[1][c], hi[2][c], hi[3][c]};
            __builtin_nontemporal_store(vlo, (v4f*)(o0 + (size_t)c * NK));
            __builtin_nontemporal_store(vhi, (v4f*)(o0 + (size_t)(4 + c) * NK));
        }
        // y channels -> out0 channels 8..15 and out1
        float acc[8][4];
        #pragma unroll
        for (int k = 0; k < 4; k++) {
            float rx = ex - qc[k].x, ry = ey - qc[k].y, rz = ez - qc[k].z;
            float dist = sqrtf(rx * rx + ry * ry + rz * rz);
            float rf[10] = {dist, rx, ry, rz, ex, ey, ez, qc[k].x, qc[k].y, qc[k].z};
            #pragma unroll
            for (int o = 0; o < 8; o++) {
                float y = bb[o];
                #pragma unroll
                for (int c = 0; c < 10; c++) y = fmaf(w[o * 10 + c], rf[c], y);
                acc[o][k] = fmaxf(y, SLOPE * y);   // LeakyReLU(0.2)
            }
        }
        #pragma unroll
        for (int o = 0; o < 8; o++) {
            v4f v = {acc[o][0], acc[o][1], acc[o][2], acc[o][3]};
            __builtin_nontemporal_store(v, (v4f*)(o0 + (size_t)(8 + o) * NK));
            __builtin_nontemporal_store(v, (v4f*)(o1 + (size_t)o * NK));
        }
    } else {
        // ---- fallback: raw gathers ----
        const float* fb = features + (size_t)b * 8 * Nn;
        #pragma unroll
        for (int d = 0; d < 8; d++) {
            v4f v = {fb[(size_t)d * Nn + id[0]], fb[(size_t)d * Nn + id[1]],
                     fb[(size_t)d * Nn + id[2]], fb[(size_t)d * Nn + id[3]]};
            __builtin_nontemporal_store(v, (v4f*)(o0 + (size_t)d * NK));
        }
        float acc[8][4];
        #pragma unroll
        for (int k = 0; k < 4; k++) {
            float nx = cb[id[k] * 3], ny = cb[id[k] * 3 + 1], nz = cb[id[k] * 3 + 2];
            float rx = ex - nx, ry = ey - ny, rz = ez - nz;
            float dist = sqrtf(rx * rx + ry * ry + rz * rz);
            float rf[10] = {dist, rx, ry, rz, ex, ey, ez, nx, ny, nz};
            #pragma unroll
            for (int o = 0; o < 8; o++) {
                float y = bb[o];
                #pragma unroll
                for (int c = 0; c < 10; c++) y = fmaf(w[o * 10 + c], rf[c], y);
                acc[o][k] = fmaxf(y, SLOPE * y);
            }
        }
        #pragma unroll
        for (int o = 0; o < 8; o++) {
            v4f v = {acc[o][0], acc[o][1], acc[o][2], acc[o][3]};
            __builtin_nontemporal_store(v, (v4f*)(o0 + (size_t)(8 + o) * NK));
            __builtin_nontemporal_store(v, (v4f*)(o1 + (size_t)o * NK));
        }
    }
}

extern "C" void kernel_launch(void* const* d_in, const int* in_sizes, int n_in,
                              void* d_out, int out_size, void* d_ws, size_t ws_size,
                              hipStream_t stream) {
    const float* coords   = (const float*)d_in[0];   // (4,65536,3)
    const float* features = (const float*)d_in[1];   // (4,8,65536,1)
    const int*   nbr      = (const int*)d_in[2];     // (4,65536,16)
    const float* conv_w   = (const float*)d_in[3];   // (8,10)
    const float* conv_b   = (const float*)d_in[4];   // (8,)
    const float* gamma    = (const float*)d_in[5];   // (8,)
    const float* beta     = (const float*)d_in[6];   // (8,)
    float* out = (float*)d_out;
    const v4i* nbr4 = (const v4i*)nbr;

    float* stats = (float*)d_ws;
    const size_t CPAD_OFF = 1024;
    const size_t CPAD_BYTES = (size_t)Bn * Nn * 4 * sizeof(float);   // 4 MB
    const size_t TF_OFF = CPAD_OFF + CPAD_BYTES;
    const size_t TF_BYTES = (size_t)Bn * Nn * 8 * sizeof(float);     // 8 MB
    const size_t NEED = TF_OFF + TF_BYTES;
    v4f* cpad = (v4f*)((char*)d_ws + CPAD_OFF);
    v4f* tf   = (v4f*)((char*)d_ws + TF_OFF);

    const bool prep = (ws_size >= NEED);
    if (prep) {
        prep_kernel<<<(Bn * Nn) / 256, 256, 0, stream>>>(coords, features, stats, cpad, tf);
        reduce_kernel<true><<<1024, 256, 0, stream>>>(nbr4, cpad, coords, conv_w, conv_b, stats);
    } else {
        init_kernel<<<1, 64, 0, stream>>>(stats);
        reduce_kernel<false><<<1024, 256, 0, stream>>>(nbr4, cpad, coords, conv_w, conv_b, stats);
    }
    finalize_kernel<<<1, 128, 0, stream>>>(conv_w, conv_b, gamma, beta, stats);
    if (prep)
        output_kernel<true><<<4096, 256, 0, stream>>>(nbr4, cpad, coords, tf, features, stats, out);
    else
        output_kernel<false><<<4096, 256, 0, stream>>>(nbr4, cpad, coords, tf, features, stats, out);
}